// Round 5
// baseline (203.494 us; speedup 1.0000x reference)
//
#include <hip/hip_runtime.h>
#include <hip/hip_bf16.h>
#include <stdint.h>

// ---------------------------------------------------------------------------
// Net_71373766525077: SNN leaky layer.
//   cur = x @ W^T   (1024x4096 @ 4096x4096 fp32; mem tol 7.92 -> bf16 MFMA)
//   scan t: reset=(mem>1); mem=0.9*mem+cur[t]-reset; spk=(mem>1)
//   out = concat(spk_rec[T][N], mem_rec[T][N]) fp32
//
// R4 -> R5:
//  * boundary pass was ~70us: per-lane-contiguous [N][T] reads = 64-way
//    gathered wave-instrs on a 64-wave latency chain. Now producer/consumer:
//    3 waves stage cur[T][N] (coalesced) into an LDS ring transposed to
//    [n][t]; 1 consumer wave runs the recurrence from LDS (~3.5us chain).
//  * replay now reads cur in [T][N] (coalesced) -> pure BW with 2048 waves.
//  * gemm: transpose epilogue dropped (cur stays [T][N]).
// ---------------------------------------------------------------------------

typedef __attribute__((ext_vector_type(8))) short bf16x8;
typedef __attribute__((ext_vector_type(4))) float floatx4;

#define T_STEPS 1024
#define N_IN    4096
#define N_OUT   4096

#define GM 64    // gemm M tile
#define GN 128   // gemm N tile
#define BKK 64   // K-chunk per LDS stage (bf16 elements)

#define CHUNK 32                  // replay chunk length
#define NCHUNK (T_STEPS / CHUNK)  // 32

#define PH_T 128                  // timesteps per pass-1 phase
#define NB_N 16                   // neurons per pass-1 block
#define TP   130                  // LDS t-stride (floats): 8B-aligned float2, <=2-way banks

__device__ __forceinline__ unsigned short f2bf_rne(float f) {
    unsigned int u = __builtin_bit_cast(unsigned int, f);
    unsigned int r = 0x7FFFu + ((u >> 16) & 1u);
    return (unsigned short)((u + r) >> 16);
}

__global__ __launch_bounds__(256) void cvt_kernel(const float4* __restrict__ in,
                                                  ushort4* __restrict__ out, int n4) {
    int i = blockIdx.x * blockDim.x + threadIdx.x;
    if (i < n4) {
        float4 v = in[i];
        ushort4 o;
        o.x = f2bf_rne(v.x);
        o.y = f2bf_rne(v.y);
        o.z = f2bf_rne(v.z);
        o.w = f2bf_rne(v.w);
        out[i] = o;
    }
}

__device__ __forceinline__ void gload16(const void* g, void* l) {
    __builtin_amdgcn_global_load_lds((const __attribute__((address_space(1))) void*)g,
                                     (__attribute__((address_space(3))) void*)l,
                                     16, 0, 0);
}

// C[T][N] = A[M][K] * B[N][K]^T, bf16 in, fp32 out. 64x128 tile / block,
// 512 blocks (2/CU). 4 waves, each 64m x 32n via 4x2 of 16x16x32 MFMA.
__global__ __launch_bounds__(256) void gemm_bt(const short* __restrict__ A,
                                               const short* __restrict__ B,
                                               float* __restrict__ C) {
    __shared__ short sA[GM * BKK];   // 8 KB
    __shared__ short sB[GN * BKK];   // 16 KB

    const int tid  = threadIdx.x;
    const int lane = tid & 63;
    const int wv   = tid >> 6;
    const int wn   = wv * 32;

    // swizzle: same n_tile -> same XCD (bid % 8 == n_tile % 8)
    const int n_tile = blockIdx.x & 31;
    const int m_tile = blockIdx.x >> 5;
    const long bm = (long)m_tile * GM;
    const long bn = (long)n_tile * GN;

    floatx4 acc[4][2] = {};

    const int srow = tid >> 3;       // 0..31
    const int scol = (tid & 7) * 8;  // bf16 offset within 64-wide row
    const short* gA[2];
    const short* gB[4];
    short* lA[2];
    short* lB[4];
#pragma unroll
    for (int p = 0; p < 2; ++p) {
        gA[p] = A + (bm + p * 32 + srow) * (long)N_IN + scol;
        lA[p] = sA + p * 2048 + tid * 8;
    }
#pragma unroll
    for (int p = 0; p < 4; ++p) {
        gB[p] = B + (bn + p * 32 + srow) * (long)N_IN + scol;
        lB[p] = sB + p * 2048 + tid * 8;
    }

    const int fm  = lane & 15;
    const int fko = (lane >> 4) * 8;

    for (int k0 = 0; k0 < N_IN; k0 += BKK) {
#pragma unroll
        for (int p = 0; p < 2; ++p) gload16(gA[p] + k0, lA[p]);
#pragma unroll
        for (int p = 0; p < 4; ++p) gload16(gB[p] + k0, lB[p]);
        __syncthreads();

#pragma unroll
        for (int ks = 0; ks < 2; ++ks) {
            bf16x8 af[4], bfr[2];
#pragma unroll
            for (int i = 0; i < 4; ++i)
                af[i] = *(const bf16x8*)(sA + (i * 16 + fm) * 64 + ks * 32 + fko);
#pragma unroll
            for (int j = 0; j < 2; ++j)
                bfr[j] = *(const bf16x8*)(sB + (wn + j * 16 + fm) * 64 + ks * 32 + fko);
#pragma unroll
            for (int i = 0; i < 4; ++i)
#pragma unroll
                for (int j = 0; j < 2; ++j)
                    acc[i][j] = __builtin_amdgcn_mfma_f32_16x16x32_bf16(
                        af[i], bfr[j], acc[i][j], 0, 0, 0);
        }
        __syncthreads();
    }

    // C/D layout: col(n)=lane&15, row(m)=(lane>>4)*4+reg [m89/m91]
    const int cn = lane & 15;
    const int cm = (lane >> 4) * 4;
#pragma unroll
    for (int i = 0; i < 4; ++i)
#pragma unroll
        for (int j = 0; j < 2; ++j)
#pragma unroll
            for (int r = 0; r < 4; ++r)
                C[(bm + i * 16 + cm + r) * (long)N_OUT + bn + wn + j * 16 + cn] =
                    acc[i][j][r];
}

// Pass 1: boundary states. 256 blocks x 256 threads; block owns NB_N=16
// neurons. Waves 0-2 stage cur[T][N] (coalesced) into LDS ring [n][t]
// (2 slots x 128 t, stride TP=130); wave 3 runs the serial recurrence from
// LDS and stores mem at every 32-step boundary: bnd[c][n].
__global__ __launch_bounds__(256) void boundary_kernel(const float* __restrict__ cur,
                                                       float* __restrict__ bnd) {
    __shared__ float ring[2][NB_N * TP];   // 16.6 KB

    const int tid  = threadIdx.x;
    const int wv   = tid >> 6;
    const int lane = tid & 63;
    const int n0   = blockIdx.x * NB_N;

    // producer lane mapping: one instr = 4 t-rows x 16 n (4 x 64 B segments)
    const int pn = lane & 15;   // neuron offset
    const int tr = lane >> 4;   // t-row within group of 4

    float mem = 0.0f;           // consumer state (wave 3)

    // ---- prefill: phase 0 -> slot 0 ----
    if (wv < 3) {
        float v[11];
        int gidx[11];
#pragma unroll
        for (int i = 0; i < 11; ++i) {
            int g = wv + 3 * i;            // row-group 0..31
            gidx[i] = g;
            if (g < 32)
                v[i] = cur[(size_t)(g * 4 + tr) * N_OUT + n0 + pn];
        }
#pragma unroll
        for (int i = 0; i < 11; ++i)
            if (gidx[i] < 32)
                ring[0][pn * TP + gidx[i] * 4 + tr] = v[i];
    }
    __syncthreads();

    for (int ph = 0; ph < T_STEPS / PH_T; ++ph) {
        if (wv < 3) {
            // stage phase ph+1 into slot (ph+1)&1
            if (ph + 1 < T_STEPS / PH_T) {
                const size_t tb = (size_t)(ph + 1) * PH_T;
                float v[11];
                int gidx[11];
#pragma unroll
                for (int i = 0; i < 11; ++i) {
                    int g = wv + 3 * i;
                    gidx[i] = g;
                    if (g < 32)
                        v[i] = cur[(tb + g * 4 + tr) * N_OUT + n0 + pn];
                }
#pragma unroll
                for (int i = 0; i < 11; ++i)
                    if (gidx[i] < 32)
                        ring[(ph + 1) & 1][pn * TP + gidx[i] * 4 + tr] = v[i];
            }
        } else {
            // consume slot ph&1: 128 steps (4 sub-blocks of 32)
            const float* base = &ring[ph & 1][pn * TP];
#pragma unroll
            for (int sub = 0; sub < 4; ++sub) {
                if (lane < 16)
                    bnd[(size_t)(ph * 4 + sub) * N_OUT + n0 + pn] = mem;
                float2 buf[16];
#pragma unroll
                for (int q = 0; q < 16; ++q)
                    buf[q] = *(const float2*)&base[sub * 32 + q * 2];
#pragma unroll
                for (int q = 0; q < 16; ++q) {
                    {
                        float rst = mem > 1.0f ? 1.0f : 0.0f;
                        mem = fmaf(0.9f, mem, buf[q].x) - rst;
                    }
                    {
                        float rst = mem > 1.0f ? 1.0f : 0.0f;
                        mem = fmaf(0.9f, mem, buf[q].y) - rst;
                    }
                }
            }
        }
        __syncthreads();
    }
}

// Pass 2: replay. Thread (n,c) restarts from bnd[c][n], recomputes steps
// [c*32, c*32+32) reading cur[T][N] coalesced, writes spk/mem coalesced.
// 2048 waves (8/CU): pure memory-bound.
__global__ __launch_bounds__(256) void replay_kernel(const float* __restrict__ cur,
                                                     const float* __restrict__ bnd,
                                                     float* __restrict__ out) {
    const int lane = threadIdx.x & 63;
    const int w    = threadIdx.x >> 6;
    const int n    = blockIdx.x * 64 + lane;      // 0..4095
    const int c    = blockIdx.y * 4 + w;          // 0..31
    float* __restrict__ spk  = out;
    float* __restrict__ memo = out + (size_t)T_STEPS * N_OUT;

    float mem = bnd[(size_t)c * N_OUT + n];
    const float* __restrict__ p = cur + (size_t)c * CHUNK * N_OUT + n;

    float v[CHUNK];
#pragma unroll
    for (int j = 0; j < CHUNK; ++j) v[j] = p[(size_t)j * N_OUT];

#pragma unroll
    for (int j = 0; j < CHUNK; ++j) {
        float rst = mem > 1.0f ? 1.0f : 0.0f;
        mem = fmaf(0.9f, mem, v[j]) - rst;
        size_t idx = (size_t)(c * CHUNK + j) * N_OUT + n;
        spk[idx]  = mem > 1.0f ? 1.0f : 0.0f;
        memo[idx] = mem;
    }
}

extern "C" void kernel_launch(void* const* d_in, const int* in_sizes, int n_in,
                              void* d_out, int out_size, void* d_ws, size_t ws_size,
                              hipStream_t stream) {
    const float* x = (const float*)d_in[0];  // [1024][4096] fp32
    const float* W = (const float*)d_in[1];  // [4096][4096] fp32
    float* out = (float*)d_out;              // [2][1024][4096] fp32

    char* ws = (char*)d_ws;
    const size_t xbBytes = (size_t)T_STEPS * N_IN * 2;    // 8 MB
    const size_t WbBytes = (size_t)N_OUT * N_IN * 2;      // 33.6 MB
    const size_t CtBytes = (size_t)T_STEPS * N_OUT * 4;   // 16.8 MB
    short* xb  = (short*)ws;
    short* Wb  = (short*)(ws + xbBytes);
    float* cur = (float*)(ws + xbBytes + WbBytes);            // [T][N]
    float* bnd = (float*)(ws + xbBytes + WbBytes + CtBytes);  // [32][4096]

    {
        int n4 = T_STEPS * N_IN / 4;
        cvt_kernel<<<n4 / 256, 256, 0, stream>>>((const float4*)x, (ushort4*)xb, n4);
    }
    {
        int n4 = N_OUT * N_IN / 4;
        cvt_kernel<<<n4 / 256, 256, 0, stream>>>((const float4*)W, (ushort4*)Wb, n4);
    }

    gemm_bt<<<(N_OUT / GN) * (T_STEPS / GM), 256, 0, stream>>>(xb, Wb, cur);

    boundary_kernel<<<N_OUT / NB_N, 256, 0, stream>>>(cur, bnd);

    replay_kernel<<<dim3(N_OUT / 64, NCHUNK / 4), 256, 0, stream>>>(cur, bnd, out);
}

// Round 6
// 203.200 us; speedup vs baseline: 1.0014x; 1.0014x over previous
//
#include <hip/hip_runtime.h>
#include <hip/hip_bf16.h>
#include <stdint.h>

// ---------------------------------------------------------------------------
// Net_71373766525077: SNN leaky layer.
//   cur = x @ W^T   (1024x4096 @ 4096x4096 fp32; mem tol 7.92 -> bf16 MFMA)
//   scan t: reset=(mem>1); mem=0.9*mem+cur[t]-reset; spk=(mem>1)
//   out = concat(spk_rec[T][N], mem_rec[T][N]) fp32
//
// R5 -> R6:
//  * gemm: split-K S=2 (64x128 tile, 1024 blocks = 4 blocks/CU, 16 waves/CU).
//    Logical staging bytes unchanged; barrier drains per block halved.
//    Partial sum P[2][T][N]; the add is fused into boundary+replay reads.
//  * S=1 fallback if ws_size can't hold 2 partials.
//  * Also: gemm now at ~50us lowers the rocprof top-5 cutoff, exposing
//    whatever hidden dispatch holds the unexplained ~110us residual.
// ---------------------------------------------------------------------------

typedef __attribute__((ext_vector_type(8))) short bf16x8;
typedef __attribute__((ext_vector_type(4))) float floatx4;

#define T_STEPS 1024
#define N_IN    4096
#define N_OUT   4096

#define GM 64    // gemm M tile
#define GN 128   // gemm N tile
#define BKK 64   // K-chunk per LDS stage (bf16 elements)

#define CHUNK 32                  // replay chunk length
#define NCHUNK (T_STEPS / CHUNK)  // 32

#define PH_T 128                  // timesteps per pass-1 phase
#define NB_N 16                   // neurons per pass-1 block
#define TP   130                  // LDS t-stride (floats)

#define TN ((size_t)T_STEPS * N_OUT)

__device__ __forceinline__ unsigned short f2bf_rne(float f) {
    unsigned int u = __builtin_bit_cast(unsigned int, f);
    unsigned int r = 0x7FFFu + ((u >> 16) & 1u);
    return (unsigned short)((u + r) >> 16);
}

__global__ __launch_bounds__(256) void cvt_kernel(const float4* __restrict__ in,
                                                  ushort4* __restrict__ out, int n4) {
    int i = blockIdx.x * blockDim.x + threadIdx.x;
    if (i < n4) {
        float4 v = in[i];
        ushort4 o;
        o.x = f2bf_rne(v.x);
        o.y = f2bf_rne(v.y);
        o.z = f2bf_rne(v.z);
        o.w = f2bf_rne(v.w);
        out[i] = o;
    }
}

__device__ __forceinline__ void gload16(const void* g, void* l) {
    __builtin_amdgcn_global_load_lds((const __attribute__((address_space(1))) void*)g,
                                     (__attribute__((address_space(3))) void*)l,
                                     16, 0, 0);
}

// P[z][T][N] (+)= A[M][kz] * B[N][kz]^T, bf16 in, fp32 out.
// 64x128 tile, grid = 512*S blocks (bid: z = bid>>9, mt = (bid>>5)&15,
// nt = bid&31). 4 waves, each 64m x 32n via 4x2 of 16x16x32 MFMA.
__global__ __launch_bounds__(256) void gemm_bt(const short* __restrict__ A,
                                               const short* __restrict__ B,
                                               float* __restrict__ P,
                                               int kLen) {
    __shared__ short sA[GM * BKK];   // 8 KB
    __shared__ short sB[GN * BKK];   // 16 KB

    const int tid  = threadIdx.x;
    const int lane = tid & 63;
    const int wv   = tid >> 6;
    const int wn   = wv * 32;

    const int bid    = blockIdx.x;
    const int z      = bid >> 9;       // split-K index (0 when grid=512)
    const int n_tile = bid & 31;
    const int m_tile = (bid >> 5) & 15;
    const long bm = (long)m_tile * GM;
    const long bn = (long)n_tile * GN;
    const int kBeg = z * kLen;
    const int kEnd = kBeg + kLen;
    float* __restrict__ Pz = P + (size_t)z * TN;

    floatx4 acc[4][2] = {};

    const int srow = tid >> 3;       // 0..31
    const int scol = (tid & 7) * 8;  // bf16 offset within 64-wide row
    const short* gA[2];
    const short* gB[4];
    short* lA[2];
    short* lB[4];
#pragma unroll
    for (int p = 0; p < 2; ++p) {
        gA[p] = A + (bm + p * 32 + srow) * (long)N_IN + scol;
        lA[p] = sA + p * 2048 + tid * 8;
    }
#pragma unroll
    for (int p = 0; p < 4; ++p) {
        gB[p] = B + (bn + p * 32 + srow) * (long)N_IN + scol;
        lB[p] = sB + p * 2048 + tid * 8;
    }

    const int fm  = lane & 15;
    const int fko = (lane >> 4) * 8;

    for (int k0 = kBeg; k0 < kEnd; k0 += BKK) {
#pragma unroll
        for (int p = 0; p < 2; ++p) gload16(gA[p] + k0, lA[p]);
#pragma unroll
        for (int p = 0; p < 4; ++p) gload16(gB[p] + k0, lB[p]);
        __syncthreads();

#pragma unroll
        for (int ks = 0; ks < 2; ++ks) {
            bf16x8 af[4], bfr[2];
#pragma unroll
            for (int i = 0; i < 4; ++i)
                af[i] = *(const bf16x8*)(sA + (i * 16 + fm) * 64 + ks * 32 + fko);
#pragma unroll
            for (int j = 0; j < 2; ++j)
                bfr[j] = *(const bf16x8*)(sB + (wn + j * 16 + fm) * 64 + ks * 32 + fko);
#pragma unroll
            for (int i = 0; i < 4; ++i)
#pragma unroll
                for (int j = 0; j < 2; ++j)
                    acc[i][j] = __builtin_amdgcn_mfma_f32_16x16x32_bf16(
                        af[i], bfr[j], acc[i][j], 0, 0, 0);
        }
        __syncthreads();
    }

    // C/D layout: col(n)=lane&15, row(m)=(lane>>4)*4+reg [m89/m91]
    const int cn = lane & 15;
    const int cm = (lane >> 4) * 4;
#pragma unroll
    for (int i = 0; i < 4; ++i)
#pragma unroll
        for (int j = 0; j < 2; ++j)
#pragma unroll
            for (int r = 0; r < 4; ++r)
                Pz[(bm + i * 16 + cm + r) * (long)N_OUT + bn + wn + j * 16 + cn] =
                    acc[i][j][r];
}

// Pass 1: boundary states. 256 blocks x 256 threads; block owns NB_N=16
// neurons. Waves 0-2 stage P (summing NPART partials, coalesced [T][N]) into
// LDS ring [n][t]; wave 3 runs the serial recurrence from LDS and stores mem
// at every 32-step boundary: bnd[c][n].
template <int NPART>
__global__ __launch_bounds__(256) void boundary_kernel(const float* __restrict__ P,
                                                       float* __restrict__ bnd) {
    __shared__ float ring[2][NB_N * TP];   // 16.6 KB

    const int tid  = threadIdx.x;
    const int wv   = tid >> 6;
    const int lane = tid & 63;
    const int n0   = blockIdx.x * NB_N;

    const int pn = lane & 15;   // neuron offset
    const int tr = lane >> 4;   // t-row within group of 4

    float mem = 0.0f;           // consumer state (wave 3)

    // ---- prefill: phase 0 -> slot 0 ----
    if (wv < 3) {
        float v0[11], v1[11];
        int gidx[11];
#pragma unroll
        for (int i = 0; i < 11; ++i) {
            int g = wv + 3 * i;
            gidx[i] = g;
            if (g < 32) {
                size_t idx = (size_t)(g * 4 + tr) * N_OUT + n0 + pn;
                v0[i] = P[idx];
                if (NPART == 2) v1[i] = P[TN + idx];
            }
        }
#pragma unroll
        for (int i = 0; i < 11; ++i)
            if (gidx[i] < 32)
                ring[0][pn * TP + gidx[i] * 4 + tr] =
                    (NPART == 2) ? (v0[i] + v1[i]) : v0[i];
    }
    __syncthreads();

    for (int ph = 0; ph < T_STEPS / PH_T; ++ph) {
        if (wv < 3) {
            if (ph + 1 < T_STEPS / PH_T) {
                const size_t tb = (size_t)(ph + 1) * PH_T;
                float v0[11], v1[11];
                int gidx[11];
#pragma unroll
                for (int i = 0; i < 11; ++i) {
                    int g = wv + 3 * i;
                    gidx[i] = g;
                    if (g < 32) {
                        size_t idx = (tb + g * 4 + tr) * N_OUT + n0 + pn;
                        v0[i] = P[idx];
                        if (NPART == 2) v1[i] = P[TN + idx];
                    }
                }
#pragma unroll
                for (int i = 0; i < 11; ++i)
                    if (gidx[i] < 32)
                        ring[(ph + 1) & 1][pn * TP + gidx[i] * 4 + tr] =
                            (NPART == 2) ? (v0[i] + v1[i]) : v0[i];
            }
        } else {
            const float* base = &ring[ph & 1][pn * TP];
#pragma unroll
            for (int sub = 0; sub < 4; ++sub) {
                if (lane < 16)
                    bnd[(size_t)(ph * 4 + sub) * N_OUT + n0 + pn] = mem;
                float2 buf[16];
#pragma unroll
                for (int q = 0; q < 16; ++q)
                    buf[q] = *(const float2*)&base[sub * 32 + q * 2];
#pragma unroll
                for (int q = 0; q < 16; ++q) {
                    {
                        float rst = mem > 1.0f ? 1.0f : 0.0f;
                        mem = fmaf(0.9f, mem, buf[q].x) - rst;
                    }
                    {
                        float rst = mem > 1.0f ? 1.0f : 0.0f;
                        mem = fmaf(0.9f, mem, buf[q].y) - rst;
                    }
                }
            }
        }
        __syncthreads();
    }
}

// Pass 2: replay. Thread (n,c) restarts from bnd[c][n], recomputes steps
// [c*32, c*32+32) reading P[T][N] coalesced (summing NPART partials),
// writes spk/mem coalesced. 2048 waves.
template <int NPART>
__global__ __launch_bounds__(256) void replay_kernel(const float* __restrict__ P,
                                                     const float* __restrict__ bnd,
                                                     float* __restrict__ out) {
    const int lane = threadIdx.x & 63;
    const int w    = threadIdx.x >> 6;
    const int n    = blockIdx.x * 64 + lane;      // 0..4095
    const int c    = blockIdx.y * 4 + w;          // 0..31
    float* __restrict__ spk  = out;
    float* __restrict__ memo = out + TN;

    float mem = bnd[(size_t)c * N_OUT + n];
    const float* __restrict__ p0 = P + (size_t)c * CHUNK * N_OUT + n;
    const float* __restrict__ p1 = p0 + TN;

    float v[CHUNK];
#pragma unroll
    for (int j = 0; j < CHUNK; ++j) {
        float a = p0[(size_t)j * N_OUT];
        if (NPART == 2) a += p1[(size_t)j * N_OUT];
        v[j] = a;
    }

#pragma unroll
    for (int j = 0; j < CHUNK; ++j) {
        float rst = mem > 1.0f ? 1.0f : 0.0f;
        mem = fmaf(0.9f, mem, v[j]) - rst;
        size_t idx = (size_t)(c * CHUNK + j) * N_OUT + n;
        spk[idx]  = mem > 1.0f ? 1.0f : 0.0f;
        memo[idx] = mem;
    }
}

extern "C" void kernel_launch(void* const* d_in, const int* in_sizes, int n_in,
                              void* d_out, int out_size, void* d_ws, size_t ws_size,
                              hipStream_t stream) {
    const float* x = (const float*)d_in[0];  // [1024][4096] fp32
    const float* W = (const float*)d_in[1];  // [4096][4096] fp32
    float* out = (float*)d_out;              // [2][1024][4096] fp32

    char* ws = (char*)d_ws;
    const size_t xbBytes = (size_t)T_STEPS * N_IN * 2;    // 8 MB
    const size_t WbBytes = (size_t)N_OUT * N_IN * 2;      // 33.6 MB
    const size_t PBytes  = TN * 4;                        // 16.8 MB per partial
    const size_t bndBytes = (size_t)NCHUNK * N_OUT * 4;   // 0.5 MB
    short* xb = (short*)ws;
    short* Wb = (short*)(ws + xbBytes);
    float* P  = (float*)(ws + xbBytes + WbBytes);

    // Split-K factor (deterministic: ws_size fixed per session)
    const int S = (ws_size >= xbBytes + WbBytes + 2 * PBytes + bndBytes) ? 2 : 1;
    float* bnd = (float*)(ws + xbBytes + WbBytes + (size_t)S * PBytes);

    {
        int n4 = T_STEPS * N_IN / 4;
        cvt_kernel<<<n4 / 256, 256, 0, stream>>>((const float4*)x, (ushort4*)xb, n4);
    }
    {
        int n4 = N_OUT * N_IN / 4;
        cvt_kernel<<<n4 / 256, 256, 0, stream>>>((const float4*)W, (ushort4*)Wb, n4);
    }

    gemm_bt<<<512 * S, 256, 0, stream>>>(xb, Wb, P, N_IN / S);

    if (S == 2) {
        boundary_kernel<2><<<N_OUT / NB_N, 256, 0, stream>>>(P, bnd);
        replay_kernel<2><<<dim3(N_OUT / 64, NCHUNK / 4), 256, 0, stream>>>(P, bnd, out);
    } else {
        boundary_kernel<1><<<N_OUT / NB_N, 256, 0, stream>>>(P, bnd);
        replay_kernel<1><<<dim3(N_OUT / 64, NCHUNK / 4), 256, 0, stream>>>(P, bnd, out);
    }
}